// Round 9
// baseline (311.906 us; speedup 1.0000x reference)
//
#include <hip/hip_runtime.h>
#include <math.h>

#define NB 512
#define NPQ 128
#define NY 1024
#define NO 256
#define NTOT 1408   // NPQ+NY+NO

typedef __attribute__((ext_vector_type(8))) short bf16x8;
typedef __attribute__((ext_vector_type(4))) float f32x4;

__device__ __forceinline__ unsigned short f2bf(float f) {
    unsigned int u = __float_as_uint(f);
    u += 0x7fffu + ((u >> 16) & 1u);   // RTNE
    return (unsigned short)(u >> 16);
}
__device__ __forceinline__ float bf2f(short s) {
    return __uint_as_float(((unsigned int)(unsigned short)s) << 16);
}

union U8 { bf16x8 v; unsigned long long u[2]; };

// ============================================================================
// Kernel 0: fold weights + pre-pack W2P/BEP (unchanged from R8 — verified).
// ============================================================================
__global__ __launch_bounds__(256) void k_prep(
    const float* __restrict__ emb,  const float* __restrict__ e0b2,
    const float* __restrict__ e0w2, const float* __restrict__ wq,
    const float* __restrict__ bq,   const float* __restrict__ wk,
    const float* __restrict__ bk,   const float* __restrict__ wp,
    const float* __restrict__ bp,   const float* __restrict__ wvv,
    const float* __restrict__ bv,   const float* __restrict__ wo,
    const float* __restrict__ bo,
    const float* __restrict__ e1b2, const float* __restrict__ e1w2,
    const float* __restrict__ e2b2, const float* __restrict__ e2w2,
    float* __restrict__ Aqk, float* __restrict__ a0, float* __restrict__ P3,
    float* __restrict__ b0g0, float* __restrict__ Wvo, float* __restrict__ bvo,
    unsigned short* __restrict__ W2P, float* __restrict__ BEP)
{
    const int tid = threadIdx.x;
    __shared__ float sW2q[4096];
    __shared__ float scq[64];

    const float* w2s[3] = {e0w2, e1w2, e2w2};
    for (int idx = tid; idx < 1536; idx += 256) {
        const int t = idx >> 9, rem = idx & 511;
        const int mt = rem >> 7, rem2 = rem & 127;
        const int kh = rem2 >> 6, lane = rem2 & 63;
        const int quad = lane >> 4, lq = lane & 15;
        const float* w2 = w2s[t];
        unsigned short v[8];
        #pragma unroll
        for (int j = 0; j < 8; ++j)
            v[j] = f2bf(w2[(kh*32 + quad*8 + j)*64 + mt*16 + lq]);
        unsigned int u[4];
        #pragma unroll
        for (int p = 0; p < 4; ++p)
            u[p] = (unsigned int)v[2*p] | ((unsigned int)v[2*p+1] << 16);
        *(uint4*)&W2P[(size_t)idx*8] = make_uint4(u[0], u[1], u[2], u[3]);
    }
    const float* b2s[3] = {e0b2, e1b2, e2b2};
    for (int idx = tid; idx < 192; idx += 256) {
        const int t = idx >> 6, d = idx & 63;
        BEP[idx] = b2s[t][d] + emb[t*64 + d];
    }

    for (int idx = tid; idx < 4096; idx += 256) {
        const int h = idx >> 6, j = idx & 63;
        float s = 0.f;
        for (int e = 0; e < 64; ++e) s += e0w2[h*64+e] * wq[e*64+j];
        sW2q[idx] = s;
    }
    if (tid < 64) {
        const int j = tid;
        float s = bq[j];
        for (int e = 0; e < 64; ++e) s += (e0b2[e] + emb[e]) * wq[e*64+j];
        scq[j] = s;
    }
    for (int idx = tid; idx < 4096; idx += 256) {
        const int e = idx >> 6, o = idx & 63;
        float s = 0.f;
        for (int d = 0; d < 64; ++d) s += wvv[e*64+d] * wo[d*64+o];
        Wvo[idx] = s;
    }
    if (tid < 64) {
        const int o = tid;
        float s = bo[o];
        for (int d = 0; d < 64; ++d) s += bv[d] * wo[d*64+o];
        bvo[o] = s;
    }
    __syncthreads();
    for (int idx = tid; idx < 4096; idx += 256) {
        const int h = idx >> 6, d = idx & 63;
        float s = 0.f;
        for (int j = 0; j < 64; ++j) s += sW2q[h*64+j] * wk[d*64+j];
        Aqk[h*64+d] = s;
    }
    if (tid < 64) {
        const int d = tid;
        float s = 0.f;
        for (int j = 0; j < 64; ++j) s += scq[j] * wk[d*64+j];
        a0[d] = s;
    }
    for (int i = tid; i < 1024; i += 256) {
        const int c = i >> 6, h = i & 63;
        float s = 0.f;
        if (c == 0 || c == 1) {
            for (int j = 0; j < 64; ++j) s += sW2q[h*64+j] * wp[c*64+j];
        } else if (c == 2) {
            for (int j = 0; j < 64; ++j) s += sW2q[h*64+j] * (bp[j] + bk[j]);
        }
        P3[i] = s;
    }
    if (tid == 0) {
        float s0 = 0.f, s1 = 0.f, s2 = 0.f;
        for (int j = 0; j < 64; ++j) {
            s0 += scq[j] * wp[j];
            s1 += scq[j] * wp[64+j];
            s2 += scq[j] * (bp[j] + bk[j]);
        }
        b0g0[0] = s0; b0g0[1] = s1; b0g0[2] = s2;
    }
}

// ============================================================================
// Kernel 1: entity encoders, registers-only (unchanged from R8 — verified).
// ============================================================================
__global__ __launch_bounds__(256) void k_encode(
    const float* __restrict__ pred, const float* __restrict__ prey,
    const float* __restrict__ obst,
    const unsigned short* __restrict__ W2P, const float* __restrict__ BEP,
    const float* __restrict__ e0w1, const float* __restrict__ e0b1,
    const float* __restrict__ e1w1, const float* __restrict__ e1b1,
    const float* __restrict__ e2w1, const float* __restrict__ e2b1,
    unsigned short* __restrict__ X, float* __restrict__ POS)
{
    const int blk = blockIdx.x;
    int type, lrow0, cin, lsh, nmask, nbase;
    const float *st, *w1, *b1;
    if (blk < 512)       { type=0; lrow0=blk*128;        st=pred; w1=e0w1; b1=e0b1; cin=2; lsh=7;  nmask=NPQ-1; nbase=0; }
    else if (blk < 4608) { type=1; lrow0=(blk-512)*128;  st=prey; w1=e1w1; b1=e1b1; cin=2; lsh=10; nmask=NY-1;  nbase=NPQ; }
    else                 { type=2; lrow0=(blk-4608)*128; st=obst; w1=e2w1; b1=e2b1; cin=3; lsh=8;  nmask=NO-1;  nbase=NPQ+NY; }

    const int tid = threadIdx.x, lane = tid & 63, w = tid >> 6;
    const int lq = lane & 15, quad = lane >> 4;

    bf16x8 wfrag[4][2];
    #pragma unroll
    for (int mt = 0; mt < 4; ++mt)
        #pragma unroll
        for (int kh = 0; kh < 2; ++kh)
            wfrag[mt][kh] = *(const bf16x8*)&W2P[(size_t)(((type*4 + mt)*2 + kh)*64 + lane)*8];

    float4 be[4];
    #pragma unroll
    for (int mt = 0; mt < 4; ++mt)
        be[mt] = *(const float4*)&BEP[type*64 + mt*16 + quad*4];

    float b1v[2][8], w0v[2][8], w1v[2][8], w2v[2][8];
    #pragma unroll
    for (int kh = 0; kh < 2; ++kh) {
        const int k0 = kh*32 + quad*8;
        *(float4*)&b1v[kh][0] = *(const float4*)&b1[k0];
        *(float4*)&b1v[kh][4] = *(const float4*)&b1[k0+4];
        *(float4*)&w0v[kh][0] = *(const float4*)&w1[k0];
        *(float4*)&w0v[kh][4] = *(const float4*)&w1[k0+4];
        *(float4*)&w1v[kh][0] = *(const float4*)&w1[64+k0];
        *(float4*)&w1v[kh][4] = *(const float4*)&w1[64+k0+4];
        if (cin == 3) {
            *(float4*)&w2v[kh][0] = *(const float4*)&w1[128+k0];
            *(float4*)&w2v[kh][4] = *(const float4*)&w1[128+k0+4];
        }
    }

    {
        const int r = tid >> 1, c = tid & 1;
        const int lr = lrow0 + r;
        const int pb = lr >> lsh, n = nbase + (lr & nmask);
        POS[((size_t)pb*NTOT + n)*2 + c] = st[(size_t)lr*cin + c];
    }

    #pragma unroll
    for (int rt = 0; rt < 2; ++rt) {
        const int lr = lrow0 + w*32 + rt*16 + lq;
        float s0, s1, s2 = 0.f;
        if (cin == 2) {
            const float2 sv = *(const float2*)&st[(size_t)lr*2];
            s0 = sv.x; s1 = sv.y;
        } else {
            const float2 sv = *(const float2*)&st[(size_t)lr*3];
            s0 = sv.x; s1 = sv.y; s2 = st[(size_t)lr*3 + 2];
        }
        bf16x8 hb[2];
        #pragma unroll
        for (int kh = 0; kh < 2; ++kh)
            #pragma unroll
            for (int j = 0; j < 8; ++j) {
                float a = b1v[kh][j] + s0*w0v[kh][j] + s1*w1v[kh][j];
                if (cin == 3) a += s2*w2v[kh][j];
                hb[kh][j] = (short)f2bf(fmaxf(a, 0.f));
            }

        f32x4 acc[4];
        #pragma unroll
        for (int mt = 0; mt < 4; ++mt) acc[mt] = (f32x4){0.f,0.f,0.f,0.f};
        #pragma unroll
        for (int mt = 0; mt < 4; ++mt) {
            acc[mt] = __builtin_amdgcn_mfma_f32_16x16x32_bf16(wfrag[mt][0], hb[0], acc[mt], 0, 0, 0);
            acc[mt] = __builtin_amdgcn_mfma_f32_16x16x32_bf16(wfrag[mt][1], hb[1], acc[mt], 0, 0, 0);
        }

        const int bb = lr >> lsh, n = nbase + (lr & nmask);
        unsigned short* xbase = X + ((size_t)bb*NTOT + n)*64;
        #pragma unroll
        for (int mt = 0; mt < 4; ++mt) {
            const unsigned int u0 = (unsigned int)f2bf(acc[mt][0] + be[mt].x)
                                  | ((unsigned int)f2bf(acc[mt][1] + be[mt].y) << 16);
            const unsigned int u1 = (unsigned int)f2bf(acc[mt][2] + be[mt].z)
                                  | ((unsigned int)f2bf(acc[mt][3] + be[mt].w) << 16);
            *(uint2*)(xbase + mt*16 + quad*4) = make_uint2(u0, u1);
        }
    }
}

// ============================================================================
// Kernel 2: queries from folded weights (unchanged from R6 — verified).
// ============================================================================
__global__ __launch_bounds__(256) void k_query(
    const float* __restrict__ pred,
    const float* __restrict__ e0w1, const float* __restrict__ e0b1,
    const float* __restrict__ Aqk,  const float* __restrict__ a0,
    const float* __restrict__ P3,   const float* __restrict__ b0g0,
    float* __restrict__ QT, float* __restrict__ QP, float* __restrict__ QC)
{
    const int tid = threadIdx.x, b = blockIdx.x;
    const int w = tid >> 6, lane = tid & 63, lq = lane & 15, quad = lane >> 4;
    __shared__ __align__(16) short sH[4][32][68];

    const float w1r0 = e0w1[lane], w1r1 = e0w1[64+lane], b1r = e0b1[lane];
    {
        const float* sp = pred + ((size_t)b*NPQ + w*32)*2;
        #pragma unroll
        for (int r = 0; r < 32; ++r) {
            const float a = b1r + sp[2*r]*w1r0 + sp[2*r+1]*w1r1;
            sH[w][r][lane] = (short)f2bf(fmaxf(a, 0.f));
        }
    }

    bf16x8 wfrag[4][2], a3[2];
    #pragma unroll
    for (int mt = 0; mt < 4; ++mt)
        #pragma unroll
        for (int kh = 0; kh < 2; ++kh)
            #pragma unroll
            for (int j = 0; j < 8; ++j)
                wfrag[mt][kh][j] = (short)f2bf(Aqk[(kh*32 + quad*8 + j)*64 + mt*16 + lq]);
    #pragma unroll
    for (int kh = 0; kh < 2; ++kh)
        #pragma unroll
        for (int j = 0; j < 8; ++j)
            a3[kh][j] = (short)f2bf(P3[lq*64 + kh*32 + quad*8 + j]);

    float4 a0r[4];
    #pragma unroll
    for (int mt = 0; mt < 4; ++mt) a0r[mt] = *(const float4*)&a0[mt*16 + quad*4];
    const float c0 = b0g0[0], c1 = b0g0[1], c2 = b0g0[2];

    __syncthreads();

    for (int bt = 0; bt < 2; ++bt) {
        U8 hb0, hb1;
        const short* hp = &sH[w][bt*16 + lq][0];
        hb0.u[0] = *(const unsigned long long*)(hp + quad*8);
        hb0.u[1] = *(const unsigned long long*)(hp + quad*8 + 4);
        hb1.u[0] = *(const unsigned long long*)(hp + 32 + quad*8);
        hb1.u[1] = *(const unsigned long long*)(hp + 32 + quad*8 + 4);

        f32x4 acc[4], acc3;
        #pragma unroll
        for (int mt = 0; mt < 4; ++mt) acc[mt] = (f32x4){0.f,0.f,0.f,0.f};
        acc3 = (f32x4){0.f,0.f,0.f,0.f};
        #pragma unroll
        for (int mt = 0; mt < 4; ++mt) {
            acc[mt] = __builtin_amdgcn_mfma_f32_16x16x32_bf16(wfrag[mt][0], hb0.v, acc[mt], 0, 0, 0);
            acc[mt] = __builtin_amdgcn_mfma_f32_16x16x32_bf16(wfrag[mt][1], hb1.v, acc[mt], 0, 0, 0);
        }
        acc3 = __builtin_amdgcn_mfma_f32_16x16x32_bf16(a3[0], hb0.v, acc3, 0, 0, 0);
        acc3 = __builtin_amdgcn_mfma_f32_16x16x32_bf16(a3[1], hb1.v, acc3, 0, 0, 0);

        const int row = b*NPQ + w*32 + bt*16 + lq;
        #pragma unroll
        for (int mt = 0; mt < 4; ++mt) {
            *(float4*)&QT[(size_t)row*64 + mt*16 + quad*4] = make_float4(
                acc[mt][0] + a0r[mt].x, acc[mt][1] + a0r[mt].y,
                acc[mt][2] + a0r[mt].z, acc[mt][3] + a0r[mt].w);
        }
        if (quad == 0) {
            const float qp0 = acc3[0] + c0, qp1 = acc3[1] + c1, qs = acc3[2] + c2;
            const float p0 = pred[(size_t)row*2], p1 = pred[(size_t)row*2 + 1];
            QP[(size_t)row*2]     = qp0;
            QP[(size_t)row*2 + 1] = qp1;
            QC[row] = qp0*p0 + qp1*p1 + qs;
        }
    }
}

// ============================================================================
// Kernel 3 (R9): flash attention, key-split. 1024 blocks = (batch, key-half);
// 11 tiles each. Fixed-exponent softmax => halves combine exactly:
// O = (O0+O1)/(l0+l1), done in k_head's prologue. Writes unnormalized O (bf16,
// same quantization the old k_head applied) + l (f32). Scale E folded into
// aq/qcr/qp at load. Loop parity is LOCAL tile index t (11 odd => final PV
// reads sXc[(11-1)&1] = sXc[0]). Hazard structure identical to R7/R8.
// ============================================================================
__global__ __launch_bounds__(256, 2) void k_attn(
    const unsigned short* __restrict__ X, const float* __restrict__ POS,
    const float* __restrict__ QT, const float* __restrict__ QP,
    const float* __restrict__ QC,
    unsigned short* __restrict__ OH, float* __restrict__ LH)
{
    const int tid = threadIdx.x;
    const int b = blockIdx.x >> 1, half = blockIdx.x & 1;
    const int kt0 = half * 11;
    const int w = tid >> 6, lane = tid & 63, lq = lane & 15, quad = lane >> 4;

    __shared__ __align__(16) short sXc[2][64][68];   // [buf][d][key] (X^T)
    __shared__ __align__(16) short sP[4][32][68];    // per-wave [q][key]

    const float E = 0.180336884f;   // (1/sqrt(64)) * log2(e), folded into aq/qc/qp

    bf16x8 aq[2][2];
    #pragma unroll
    for (int qt = 0; qt < 2; ++qt) {
        const float* qrow = QT + ((size_t)b*NPQ + w*32 + qt*16 + lq)*64;
        #pragma unroll
        for (int kh = 0; kh < 2; ++kh)
            #pragma unroll
            for (int j = 0; j < 8; ++j)
                aq[qt][kh][j] = (short)f2bf(E * qrow[kh*32 + quad*8 + j]);
    }

    float qcr[2][4], qp0r[2][4], qp1r[2][4], lacc[2][4];
    f32x4 O[2][4];
    #pragma unroll
    for (int qt = 0; qt < 2; ++qt)
        #pragma unroll
        for (int i = 0; i < 4; ++i) {
            const size_t g = (size_t)b*NPQ + w*32 + qt*16 + quad*4 + i;
            qcr[qt][i]  = E * QC[g];
            qp0r[qt][i] = -E * QP[2*g];
            qp1r[qt][i] = -E * QP[2*g+1];
            lacc[qt][i] = 0.f;
        }
    #pragma unroll
    for (int qt = 0; qt < 2; ++qt)
        #pragma unroll
        for (int nt = 0; nt < 4; ++nt) O[qt][nt] = (f32x4){0.f,0.f,0.f,0.f};

    const int skey = tid & 63, sd0 = (tid >> 6) * 16;

    for (int t = 0; t < 11; ++t) {
        const int kt = kt0 + t;
        const int par = t & 1;

        const unsigned short* gx = X + ((size_t)b*NTOT + kt*64 + skey)*64 + sd0;
        const uint4 t0 = *(const uint4*)(gx);
        const uint4 t1 = *(const uint4*)(gx + 8);

        if (t > 0) {
            const int pb = par ^ 1;
            #pragma unroll
            for (int kc = 0; kc < 2; ++kc) {
                U8 pa[2];
                #pragma unroll
                for (int qt = 0; qt < 2; ++qt) {
                    const short* pp = &sP[w][qt*16 + lq][kc*32 + quad*8];
                    pa[qt].u[0] = *(const unsigned long long*)pp;
                    pa[qt].u[1] = *(const unsigned long long*)(pp + 4);
                }
                #pragma unroll
                for (int nt = 0; nt < 4; ++nt) {
                    U8 bv;
                    const short* xp = &sXc[pb][nt*16 + lq][kc*32 + quad*8];
                    bv.u[0] = *(const unsigned long long*)xp;
                    bv.u[1] = *(const unsigned long long*)(xp + 4);
                    O[0][nt] = __builtin_amdgcn_mfma_f32_16x16x32_bf16(pa[0].v, bv.v, O[0][nt], 0, 0, 0);
                    O[1][nt] = __builtin_amdgcn_mfma_f32_16x16x32_bf16(pa[1].v, bv.v, O[1][nt], 0, 0, 0);
                }
            }
        }

        __builtin_amdgcn_sched_barrier(0);

        #pragma unroll
        for (int nt = 0; nt < 4; ++nt) {
            union U16 { bf16x8 v; uint4 u; };
            U16 bx0, bx1;
            const unsigned short* xrow = X + ((size_t)b*NTOT + kt*64 + nt*16 + lq)*64;
            bx0.u = *(const uint4*)(xrow + quad*8);
            bx1.u = *(const uint4*)(xrow + 32 + quad*8);
            const float pos0 = POS[((size_t)b*NTOT + kt*64 + nt*16 + lq)*2];
            const float pos1 = POS[((size_t)b*NTOT + kt*64 + nt*16 + lq)*2 + 1];
            #pragma unroll
            for (int qt = 0; qt < 2; ++qt) {
                f32x4 sa = (f32x4){0.f,0.f,0.f,0.f};
                sa = __builtin_amdgcn_mfma_f32_16x16x32_bf16(aq[qt][0], bx0.v, sa, 0, 0, 0);
                sa = __builtin_amdgcn_mfma_f32_16x16x32_bf16(aq[qt][1], bx1.v, sa, 0, 0, 0);
                #pragma unroll
                for (int i = 0; i < 4; ++i) {
                    float s = sa[i] + qcr[qt][i];
                    s = fmaf(qp0r[qt][i], pos0, s);
                    s = fmaf(qp1r[qt][i], pos1, s);
                    const float p = exp2f(s);
                    lacc[qt][i] += p;
                    sP[w][qt*16 + quad*4 + i][nt*16 + lq] = (short)f2bf(p);
                }
            }
        }

        {
            unsigned short tmp[16];
            *(uint4*)tmp = t0; *(uint4*)(tmp+8) = t1;
            #pragma unroll
            for (int j = 0; j < 16; ++j) sXc[par][sd0+j][skey] = (short)tmp[j];
        }

        __syncthreads();
    }

    // ---- final PV(t=10): reads sXc[(11-1)&1] = sXc[0] ----
    {
        #pragma unroll
        for (int kc = 0; kc < 2; ++kc) {
            U8 pa[2];
            #pragma unroll
            for (int qt = 0; qt < 2; ++qt) {
                const short* pp = &sP[w][qt*16 + lq][kc*32 + quad*8];
                pa[qt].u[0] = *(const unsigned long long*)pp;
                pa[qt].u[1] = *(const unsigned long long*)(pp + 4);
            }
            #pragma unroll
            for (int nt = 0; nt < 4; ++nt) {
                U8 bv;
                const short* xp = &sXc[0][nt*16 + lq][kc*32 + quad*8];
                bv.u[0] = *(const unsigned long long*)xp;
                bv.u[1] = *(const unsigned long long*)(xp + 4);
                O[0][nt] = __builtin_amdgcn_mfma_f32_16x16x32_bf16(pa[0].v, bv.v, O[0][nt], 0, 0, 0);
                O[1][nt] = __builtin_amdgcn_mfma_f32_16x16x32_bf16(pa[1].v, bv.v, O[1][nt], 0, 0, 0);
            }
        }
    }

    // ---- epilogue: write unnormalized O (bf16) + per-q l (f32) ----
    #pragma unroll
    for (int qt = 0; qt < 2; ++qt)
        #pragma unroll
        for (int i = 0; i < 4; ++i) {
            #pragma unroll
            for (int off = 1; off < 16; off <<= 1)
                lacc[qt][i] += __shfl_xor(lacc[qt][i], off);
            const int q = w*32 + qt*16 + quad*4 + i;
            if (lq == 0) LH[((size_t)b*2 + half)*NPQ + q] = lacc[qt][i];
            unsigned short* orow = OH + (((size_t)b*2 + half)*NPQ + q)*64;
            #pragma unroll
            for (int nt = 0; nt < 4; ++nt)
                orow[nt*16 + lq] = f2bf(O[qt][nt][i]);
        }
}

// ============================================================================
// Kernel 4 (R9): output head; prologue combines the two key-halves:
// sA = bf16( (O0+O1) / (l0+l1) ). Rest unchanged from R6 — verified.
// ============================================================================
__global__ __launch_bounds__(256) void k_head(
    const unsigned short* __restrict__ OH, const float* __restrict__ LH,
    const float* __restrict__ Wvo, const float* __restrict__ bvo,
    const float* __restrict__ nw1, const float* __restrict__ nb1,
    const float* __restrict__ nw2, const float* __restrict__ nb2,
    const float* __restrict__ nw3, const float* __restrict__ nb3,
    float* __restrict__ OUT)
{
    const int tid = threadIdx.x, b = blockIdx.x;
    const int w = tid >> 6, lane = tid & 63, lq = lane & 15, quad = lane >> 4;
    __shared__ __align__(16) short sA[128][68];
    __shared__ __align__(16) short sB[128][68];
    __shared__ float sw3[64];

    for (int i = tid*4; i < 8192; i += 1024) {
        const int r = i >> 6, d = i & 63;
        const size_t g0 = ((size_t)b*2 + 0)*8192 + i;
        const size_t g1 = ((size_t)b*2 + 1)*8192 + i;
        const uint2 u0 = *(const uint2*)&OH[g0];
        const uint2 u1 = *(const uint2*)&OH[g1];
        const float rl = 1.f / (LH[((size_t)b*2)*NPQ + r] + LH[((size_t)b*2 + 1)*NPQ + r]);
        unsigned short o[4];
        o[0] = f2bf((bf2f((short)(u0.x & 0xffff)) + bf2f((short)(u1.x & 0xffff))) * rl);
        o[1] = f2bf((bf2f((short)(u0.x >> 16))   + bf2f((short)(u1.x >> 16)))   * rl);
        o[2] = f2bf((bf2f((short)(u0.y & 0xffff)) + bf2f((short)(u1.y & 0xffff))) * rl);
        o[3] = f2bf((bf2f((short)(u0.y >> 16))   + bf2f((short)(u1.y >> 16)))   * rl);
        *(uint2*)&sA[r][d] = make_uint2(
            (unsigned int)o[0] | ((unsigned int)o[1] << 16),
            (unsigned int)o[2] | ((unsigned int)o[3] << 16));
    }
    if (tid < 64) sw3[tid] = nw3[tid];
    __syncthreads();

    const float* Ws[3] = {Wvo, nw1, nw2};
    const float* Bs[3] = {bvo, nb1, nb2};
    for (int l = 0; l < 3; ++l) {
        const float* W = Ws[l];
        const float* Bb = Bs[l];
        bf16x8 wfrag[4][2];
        #pragma unroll
        for (int mt = 0; mt < 4; ++mt)
            #pragma unroll
            for (int kh = 0; kh < 2; ++kh)
                #pragma unroll
                for (int j = 0; j < 8; ++j)
                    wfrag[mt][kh][j] = (short)f2bf(W[(kh*32 + quad*8 + j)*64 + mt*16 + lq]);
        float be[4][4];
        #pragma unroll
        for (int mt = 0; mt < 4; ++mt)
            #pragma unroll
            for (int i = 0; i < 4; ++i) be[mt][i] = Bb[mt*16 + quad*4 + i];

        short (*src)[68] = (l & 1) ? sB : sA;
        short (*dst)[68] = (l & 1) ? sA : sB;
        const bool doRelu = (l >= 1);

        for (int bt = 0; bt < 2; ++bt) {
            U8 hb0, hb1;
            const short* hp = &src[w*32 + bt*16 + lq][0];
            hb0.u[0] = *(const unsigned long long*)(hp + quad*8);
            hb0.u[1] = *(const unsigned long long*)(hp + quad*8 + 4);
            hb1.u[0] = *(const unsigned long long*)(hp + 32 + quad*8);
            hb1.u[1] = *(const unsigned long long*)(hp + 32 + quad*8 + 4);

            f32x4 acc[4];
            #pragma unroll
            for (int mt = 0; mt < 4; ++mt) acc[mt] = (f32x4){0.f,0.f,0.f,0.f};
            #pragma unroll
            for (int mt = 0; mt < 4; ++mt) {
                acc[mt] = __builtin_amdgcn_mfma_f32_16x16x32_bf16(wfrag[mt][0], hb0.v, acc[mt], 0, 0, 0);
                acc[mt] = __builtin_amdgcn_mfma_f32_16x16x32_bf16(wfrag[mt][1], hb1.v, acc[mt], 0, 0, 0);
            }
            const int row = w*32 + bt*16 + lq;
            #pragma unroll
            for (int mt = 0; mt < 4; ++mt) {
                float v0 = acc[mt][0] + be[mt][0];
                float v1 = acc[mt][1] + be[mt][1];
                float v2 = acc[mt][2] + be[mt][2];
                float v3 = acc[mt][3] + be[mt][3];
                if (doRelu) {
                    v0 = fmaxf(v0, 0.f); v1 = fmaxf(v1, 0.f);
                    v2 = fmaxf(v2, 0.f); v3 = fmaxf(v3, 0.f);
                }
                const unsigned int u0 = (unsigned int)f2bf(v0) | ((unsigned int)f2bf(v1) << 16);
                const unsigned int u1 = (unsigned int)f2bf(v2) | ((unsigned int)f2bf(v3) << 16);
                *(uint2*)&dst[row][mt*16 + quad*4] = make_uint2(u0, u1);
            }
        }
        __syncthreads();
    }

    if (tid < 128) {
        const int row = tid;
        float acc = nb3[0];
        #pragma unroll 16
        for (int d = 0; d < 64; ++d) acc += bf2f(sB[row][d]) * sw3[d];
        OUT[(size_t)b*NPQ + row] = tanhf(acc);
    }
}

// ============================================================================
extern "C" void kernel_launch(void* const* d_in, const int* in_sizes, int n_in,
                              void* d_out, int out_size, void* d_ws, size_t ws_size,
                              hipStream_t stream)
{
    const float* pred = (const float*)d_in[0];
    const float* prey = (const float*)d_in[1];
    const float* obst = (const float*)d_in[2];
    const float* emb  = (const float*)d_in[4];
    const float* e0w1 = (const float*)d_in[5];
    const float* e0b1 = (const float*)d_in[6];
    const float* e0w2 = (const float*)d_in[7];
    const float* e0b2 = (const float*)d_in[8];
    const float* e1w1 = (const float*)d_in[9];
    const float* e1b1 = (const float*)d_in[10];
    const float* e1w2 = (const float*)d_in[11];
    const float* e1b2 = (const float*)d_in[12];
    const float* e2w1 = (const float*)d_in[13];
    const float* e2b1 = (const float*)d_in[14];
    const float* e2w2 = (const float*)d_in[15];
    const float* e2b2 = (const float*)d_in[16];
    const float* wq  = (const float*)d_in[17];
    const float* bq  = (const float*)d_in[18];
    const float* wk  = (const float*)d_in[19];
    const float* bk  = (const float*)d_in[20];
    const float* wvv = (const float*)d_in[21];
    const float* bv  = (const float*)d_in[22];
    const float* wp  = (const float*)d_in[23];
    const float* bp  = (const float*)d_in[24];
    const float* wo  = (const float*)d_in[25];
    const float* bo  = (const float*)d_in[26];
    const float* nw1 = (const float*)d_in[27];
    const float* nb1 = (const float*)d_in[28];
    const float* nw2 = (const float*)d_in[29];
    const float* nb2 = (const float*)d_in[30];
    const float* nw3 = (const float*)d_in[31];
    const float* nb3 = (const float*)d_in[32];

    char* ws = (char*)d_ws;
    unsigned short* X = (unsigned short*)ws;          // 512*1408*64 bf16
    float* F    = (float*)(ws + 92274688);
    float* POS  = F;                 // 1,441,792
    float* QT   = POS + 1441792;     // 4,194,304
    float* QP   = QT  + 4194304;     // 131,072
    float* QC   = QP  + 131072;      // 65,536
    float* PREP = QC  + 65536;
    float* Aqk  = PREP;              // 4096
    float* a0   = Aqk + 4096;        // 64
    float* P3   = a0  + 64;          // 1024
    float* b0g0 = P3  + 1024;        // 4 (3 used)
    float* Wvo  = b0g0 + 4;          // 4096
    float* bvo  = Wvo + 4096;        // 64
    unsigned short* W2P = (unsigned short*)(bvo + 64);   // 12288 bf16
    float* BEP  = (float*)(W2P + 12288);                 // 192 f32
    float* LH   = BEP + 192;                             // 512*2*128 f32
    unsigned short* OH = (unsigned short*)(LH + 131072); // 512*2*128*64 bf16

    k_prep<<<1, 256, 0, stream>>>(emb, e0b2, e0w2, wq, bq, wk, bk, wp, bp,
        wvv, bv, wo, bo, e1b2, e1w2, e2b2, e2w2,
        Aqk, a0, P3, b0g0, Wvo, bvo, W2P, BEP);
    k_encode<<<5632, 256, 0, stream>>>(pred, prey, obst, W2P, BEP,
        e0w1, e0b1, e1w1, e1b1, e2w1, e2b1, X, POS);
    k_query<<<512, 256, 0, stream>>>(pred, e0w1, e0b1, Aqk, a0, P3, b0g0,
        QT, QP, QC);
    k_attn<<<1024, 256, 0, stream>>>(X, POS, QT, QP, QC, OH, LH);
    k_head<<<512, 256, 0, stream>>>(OH, LH, Wvo, bvo, nw1, nb1, nw2, nb2,
        nw3, nb3, (float*)d_out);
}